// Round 6
// baseline (193.930 us; speedup 1.0000x reference)
//
#include <hip/hip_runtime.h>
#include <hip/hip_bf16.h>

// LearnableDiffusionContrastiveLoss on MI355X.
// Algebra: l2norm(dm_normalized @ z) == l2norm(dm @ z) (positive row scaling
// cancels) -> skip the 10-step normalization entirely.
// positive = dm @ z via bf16 MFMA (fp32 accum), K-split partials; loss fused.
// R6: cache-set fix. zT rows padded 8192->8256 elements (16512B stride) so
// column reads stop collapsing into 16 L2 set-groups (16384B stride aliasing
// was serializing ALL B staging since R1). Structure otherwise identical to
// R5: BM=32/BK=32, 4 blocks/CU, 2-phase dbuf, gload_lds B, reg-staged A.

typedef float f32x4 __attribute__((ext_vector_type(4)));
typedef short s16x8 __attribute__((ext_vector_type(8)));

#define NN 8192
#define PZ 8256  // padded zT row stride (elements); 16512 B, breaks set-aliasing
#define DFF 256
#define NNEG 10

__device__ __forceinline__ unsigned short f2bf(float x) {
  return __builtin_bit_cast(unsigned short, __float2bfloat16(x));
}

__device__ __forceinline__ void gload_lds16(const void* g, void* l) {
  __builtin_amdgcn_global_load_lds(
      (const __attribute__((address_space(1))) void*)(void*)g,
      (__attribute__((address_space(3))) void*)l, 16, 0, 0);
}

__device__ __forceinline__ float dot4(float4 a, float4 b) {
  return a.x * b.x + a.y * b.y + a.z * b.z + a.w * b.w;
}

// ---- z [8192][256] f32  ->  zT bf16 [256][PZ] --------------------------------
__global__ void k_transpose(const float* __restrict__ z,
                            unsigned short* __restrict__ zT) {
  __shared__ float tile[64][65];
  const int bx = blockIdx.x;  // row tile 0..127
  const int by = blockIdx.y;  // col tile 0..3
  const int t = threadIdx.x;
  const int lc = t & 63, lq = t >> 6;  // 0..3
#pragma unroll
  for (int p = 0; p < 16; ++p) {
    const int lr = lq * 16 + p;
    tile[lr][lc] = z[(size_t)(bx * 64 + lr) * DFF + by * 64 + lc];
  }
  __syncthreads();
#pragma unroll
  for (int p = 0; p < 16; ++p) {
    const int tc = lq * 16 + p;  // col of z == row of zT
    zT[(size_t)(by * 64 + tc) * PZ + bx * 64 + lc] = f2bf(tile[lc][tc]);
  }
}

// ---- GEMM: part[ks] = dm[mtile, ks-slice] @ z  (BM=32, BN=256, BK=32) --------
// 4 waves; wave w owns output cols [64w, 64w+64): 2x4 16x16x32 frags.
// sA: [32 rows][40 bf16] (80B padded rows). sB: [256 cols][32 k] bf16, 64B/col,
// slot' = slot ^ ((col>>1)&3) swizzle on gload_lds SOURCE and on read.
__global__ __launch_bounds__(256, 4) void k_gemm(const float* __restrict__ dm,
                                                 const unsigned short* __restrict__ zT,
                                                 float* __restrict__ part, int KS) {
  __shared__ __align__(16) unsigned short sA[2][32 * 40];   // 2 x 2.5 KB
  __shared__ __align__(16) unsigned short sB[2][256 * 32];  // 2 x 16 KB
  const int bx = blockIdx.x;
  const int mtile = bx & 255;  // 256 mtiles of 32 rows
  const int ks = bx >> 8;
  const int klen = NN / KS;
  const int k0 = ks * klen;
  const int steps = klen / 32;  // 64 for KS=4
  const int tid = threadIdx.x;
  const int w = tid >> 6;
  const int l = tid & 63;
  const int m0 = mtile * 32;

  // A staging: thread -> one float4 of dm per step
  const int arow = tid >> 3;       // 0..31
  const int acol = (tid & 7) * 4;  // 0..28
  const float* asrc = dm + (size_t)(m0 + arow) * NN + k0 + acol;

  // B staging: per wave 4 instrs, 16 cols x 64B each; source pre-swizzle
  const int bss = (l & 3) ^ ((l >> 3) & 3);  // swizzled 16B slot in col
  const int bcol_i = l >> 2;                 // col within instr 0..15

  const int kw = l >> 4;    // k sub-chunk 0..3
  const int r16 = l & 15;

  f32x4 acc[2][4] = {};
  float4 areg;

#define LOAD_A(t_) areg = *(const float4*)(asrc + (t_)*32);

#define WRITE_A(s_)                                                            \
  {                                                                            \
    ushort4 h_;                                                                \
    h_.x = f2bf(areg.x); h_.y = f2bf(areg.y);                                  \
    h_.z = f2bf(areg.z); h_.w = f2bf(areg.w);                                  \
    *(ushort4*)&sA[s_][arow * 40 + acol] = h_;                                 \
  }

#define STAGE_B(t_, s_)                                                        \
  {                                                                            \
    const int kb_ = k0 + (t_)*32;                                              \
    _Pragma("unroll") for (int j = 0; j < 4; ++j) {                            \
      const int col_ = 64 * w + 16 * j + bcol_i;                               \
      gload_lds16((const char*)zT + ((size_t)col_ * PZ + kb_) * 2 + bss * 16,  \
                  (char*)sB[s_] + (64 * w + 16 * j) * 64);                     \
    }                                                                          \
  }

#define COMPUTE(s_)                                                            \
  {                                                                            \
    s16x8 af[2], bfr[4];                                                       \
    _Pragma("unroll") for (int mi = 0; mi < 2; ++mi)                           \
        af[mi] = *(const s16x8*)&sA[s_][(mi * 16 + r16) * 40 + kw * 8];        \
    _Pragma("unroll") for (int nj = 0; nj < 4; ++nj) {                         \
      const int c_ = 64 * w + nj * 16 + r16;                                   \
      const int p_ = kw ^ ((r16 >> 1) & 3);                                    \
      bfr[nj] = *(const s16x8*)&sB[s_][c_ * 32 + p_ * 8];                      \
    }                                                                          \
    _Pragma("unroll") for (int mi = 0; mi < 2; ++mi)                           \
      _Pragma("unroll") for (int nj = 0; nj < 4; ++nj)                         \
        acc[mi][nj] = __builtin_amdgcn_mfma_f32_16x16x32_bf16(                 \
            af[mi], bfr[nj], acc[mi][nj], 0, 0, 0);                            \
  }

  // prologue
  STAGE_B(0, 0);
  LOAD_A(0);
  WRITE_A(0);
  __syncthreads();

  for (int t = 0; t < steps; ++t) {
    const int cur = t & 1, nxt = cur ^ 1;
    if (t + 1 < steps) {
      LOAD_A(t + 1);
      STAGE_B(t + 1, nxt);
    }
    COMPUTE(cur);
    if (t + 1 < steps) WRITE_A(nxt);
    __syncthreads();
  }

#undef LOAD_A
#undef WRITE_A
#undef STAGE_B
#undef COMPUTE

  // epilogue: C/D layout col=lane&15, row=(lane>>4)*4+reg  [verified m89/m91]
  float* cb = part + (size_t)ks * NN * DFF;
#pragma unroll
  for (int mi = 0; mi < 2; ++mi)
#pragma unroll
    for (int nj = 0; nj < 4; ++nj) {
      const int col = w * 64 + nj * 16 + r16;
      const int row0 = m0 + mi * 16 + kw * 4;
#pragma unroll
      for (int r = 0; r < 4; ++r)
        cb[(size_t)(row0 + r) * DFF + col] = acc[mi][nj][r];
    }
}

// ---- fused loss: neg norms, K-split partial sum, norms, log-sum-exp ----------
__global__ __launch_bounds__(256) void k_loss(const float* __restrict__ z,
                                              const float* __restrict__ part,
                                              const int* __restrict__ neg_idx,
                                              float* __restrict__ lpart, int KS) {
  __shared__ float sneg[NNEG * DFF];
  __shared__ float swsum[4];
  const int t = threadIdx.x;
  const int w = t >> 6, l = t & 63;
  // normalized negatives (redundant per block; 10 KB)
  for (int k = w; k < NNEG; k += 4) {
    const int idx = neg_idx[k];
    float4 v = *(const float4*)(z + (size_t)idx * DFF + l * 4);
    float ss = dot4(v, v);
#pragma unroll
    for (int off = 32; off > 0; off >>= 1) ss += __shfl_xor(ss, off);
    const float s = 1.0f / fmaxf(sqrtf(ss), 1e-12f);
    float4 o;
    o.x = v.x * s; o.y = v.y * s; o.z = v.z * s; o.w = v.w * s;
    *(float4*)&sneg[k * DFF + l * 4] = o;
  }
  __syncthreads();
  const int gw = blockIdx.x * 4 + w;  // 0..1023, 8 rows each
  float lsum = 0.f;
  for (int rr = 0; rr < 8; ++rr) {
    const int i = gw * 8 + rr;
    const float4 a = *(const float4*)(z + (size_t)i * DFF + l * 4);
    float4 p; p.x = 0.f; p.y = 0.f; p.z = 0.f; p.w = 0.f;
    for (int ksp = 0; ksp < KS; ++ksp) {
      const float4 q = *(const float4*)(part + ((size_t)ksp * NN + i) * DFF + l * 4);
      p.x += q.x; p.y += q.y; p.z += q.z; p.w += q.w;
    }
    float vals[13];
    vals[0] = dot4(a, a);
    vals[1] = dot4(p, p);
    vals[2] = dot4(a, p);
#pragma unroll
    for (int k = 0; k < NNEG; ++k) {
      const float4 nv = *(const float4*)&sneg[k * DFF + l * 4];
      vals[3 + k] = dot4(a, nv);
    }
#pragma unroll
    for (int off = 32; off > 0; off >>= 1)
#pragma unroll
      for (int j = 0; j < 13; ++j) vals[j] += __shfl_xor(vals[j], off);
    const float na = fmaxf(sqrtf(vals[0]), 1e-12f);
    const float npp = fmaxf(sqrtf(vals[1]), 1e-12f);
    const float ps = vals[2] / (na * npp) * 5.0f;  // 1/TEMP
    float S = 0.f;
#pragma unroll
    for (int k = 0; k < NNEG; ++k) S += expf(vals[3 + k] / na * 5.0f);
    lsum += logf(expf(ps) + S) - ps;
  }
  if (l == 0) swsum[w] = lsum;
  __syncthreads();
  if (t == 0) lpart[blockIdx.x] = swsum[0] + swsum[1] + swsum[2] + swsum[3];
}

__global__ void k_final(const float* __restrict__ lpart, float* __restrict__ out) {
  const int t = threadIdx.x;  // 64
  float v = lpart[t] + lpart[t + 64] + lpart[t + 128] + lpart[t + 192];
#pragma unroll
  for (int off = 32; off > 0; off >>= 1) v += __shfl_xor(v, off);
  if (t == 0) out[0] = v * (1.0f / (float)NN);
}

extern "C" void kernel_launch(void* const* d_in, const int* in_sizes, int n_in,
                              void* d_out, int out_size, void* d_ws, size_t ws_size,
                              hipStream_t stream) {
  const float* z = (const float*)d_in[0];
  const float* dm = (const float*)d_in[1];
  // d_in[2] edge_index, d_in[3] reliable_negatives: unused by the forward pass
  const int* neg_idx = (const int*)d_in[4];
  float* out = (float*)d_out;

  // workspace: zT padded (8MB slot) | partials (KS*8MB) | lpart (1KB)
  auto need = [](size_t ks) {
    return (size_t)8 * 1024 * 1024 + ks * (size_t)NN * DFF * 4 + 1024;
  };
  int KS = 4;
  if (ws_size < need(4)) KS = (ws_size >= need(2)) ? 2 : 1;

  char* ws = (char*)d_ws;
  unsigned short* zT = (unsigned short*)ws;
  float* part = (float*)(ws + (size_t)8 * 1024 * 1024);
  float* lpart = (float*)(ws + (size_t)8 * 1024 * 1024 + (size_t)KS * NN * DFF * 4);

  k_transpose<<<dim3(128, 4), 256, 0, stream>>>(z, zT);
  k_gemm<<<256 * KS, 256, 0, stream>>>(dm, zT, part, KS);
  k_loss<<<256, 256, 0, stream>>>(z, part, neg_idx, lpart, KS);
  k_final<<<1, 64, 0, stream>>>(lpart, out);
}

// Round 7
// 123.608 us; speedup vs baseline: 1.5689x; 1.5689x over previous
//
#include <hip/hip_runtime.h>
#include <hip/hip_bf16.h>

// LearnableDiffusionContrastiveLoss on MI355X.
// Algebra: l2norm(dm_normalized @ z) == l2norm(dm @ z) (positive row scaling
// cancels) -> skip the 10-step normalization entirely.
// R7: request-rate fix. All rounds plateaued at ~1 line/cy/CU of staging
// traffic -> minimize lines: BM=128 (B redundancy 256->64 re-reads), K-packed
// zp layout so every B stage is contiguous 1KB global_load_lds, KS=8 with
// bf16 partials. A (dm f32) compulsory 256MB HBM read is the target floor.

typedef float f32x4 __attribute__((ext_vector_type(4)));
typedef short s16x8 __attribute__((ext_vector_type(8)));

#define NN 8192
#define DFF 256
#define NNEG 10

__device__ __forceinline__ unsigned short f2bf(float x) {
  return __builtin_bit_cast(unsigned short, __float2bfloat16(x));
}

__device__ __forceinline__ float bf2f(unsigned short u) {
  return __builtin_bit_cast(float, (unsigned int)u << 16);
}

__device__ __forceinline__ void gload_lds16(const void* g, void* l) {
  __builtin_amdgcn_global_load_lds(
      (const __attribute__((address_space(1))) void*)(void*)g,
      (__attribute__((address_space(3))) void*)l, 16, 0, 0);
}

__device__ __forceinline__ float dot4(float4 a, float4 b) {
  return a.x * b.x + a.y * b.y + a.z * b.z + a.w * b.w;
}

// ---- pack z [8192][256] f32 -> zp bf16 [kchunk 256][kw 4][col 256][ke 8] -----
// zp elem offset(k,d) = (k>>5)*8192 + ((k>>3)&3)*2048 + d*8 + (k&7)
// so each GEMM K-step (32 k x 256 d) is one contiguous 16KB chunk.
__global__ void k_pack(const float* __restrict__ z,
                       unsigned short* __restrict__ zp) {
  __shared__ float tile[64][65];
  const int bx = blockIdx.x;  // k tile 0..127
  const int by = blockIdx.y;  // d tile 0..3
  const int t = threadIdx.x;
  const int lc = t & 63, lq = t >> 6;  // 0..3
#pragma unroll
  for (int p = 0; p < 16; ++p) {
    const int kr = lq * 16 + p;
    tile[kr][lc] = z[(size_t)(bx * 64 + kr) * DFF + by * 64 + lc];
  }
  __syncthreads();
#pragma unroll
  for (int p2 = 0; p2 < 2; ++p2) {
    const int ko = lq * 2 + p2;  // k-octet within tile, 0..7
    s16x8 v;
#pragma unroll
    for (int ke = 0; ke < 8; ++ke) v[ke] = (short)f2bf(tile[ko * 8 + ke][lc]);
    const int chunk = bx * 2 + (ko >> 2);
    const int kw = ko & 3;
    const int d = by * 64 + lc;
    *(s16x8*)(zp + (size_t)chunk * 8192 + kw * 2048 + d * 8) = v;
  }
}

// ---- GEMM: part[ks] = dm[mtile, ks-slice] @ z  (BM=128, BN=256, BK=32) -------
// 512 thr / 8 waves, wave (wm,wn) = (w>>2, w&3) owns rows [wm*64,+64) x cols
// [wn*64,+64): 4x4 16x16x32 frags. LDS (dbuf 48KB):
//   sA: [kw 4][row 128][ke 8] bf16 8KB (reg-staged f32->bf16, linear writes)
//   sB: [kw 4][col 256][ke 8] bf16 16KB (= zp chunk, byte-linear gload_lds)
// Frag reads: 16 lanes read 256B contiguous -> conflict-free.
__global__ __launch_bounds__(512, 2) void k_gemm(const float* __restrict__ dm,
                                                 const unsigned short* __restrict__ zp,
                                                 unsigned short* __restrict__ part,
                                                 int KS) {
  __shared__ __align__(16) unsigned short sA[2][4096];  // 2 x 8 KB
  __shared__ __align__(16) unsigned short sB[2][8192];  // 2 x 16 KB
  const int bx = blockIdx.x;
  const int mtile = bx & 63;  // 64 mtiles of 128 rows
  const int ks = bx >> 6;
  const int klen = NN / KS;
  const int k0 = ks * klen;
  const int c0 = k0 >> 5;       // first K-chunk
  const int steps = klen / 32;  // 32 for KS=8
  const int tid = threadIdx.x;
  const int w = tid >> 6;
  const int l = tid & 63;
  const int m0 = mtile * 128;

  // A staging: thread owns 8 consecutive k of one row (2 float4 -> 1 s16x8)
  const int arow = w * 16 + (l & 15);  // 0..127
  const int akw = l >> 4;              // 0..3
  const float* asrc = dm + (size_t)(m0 + arow) * NN + k0 + akw * 8;

  const int r16 = l & 15, kw = l >> 4;
  const int wm = w >> 2, wn = w & 3;

  f32x4 acc[4][4] = {};
  float4 a0, a1;

#define LOAD_A(t_)                                                             \
  {                                                                            \
    a0 = *(const float4*)(asrc + (t_)*32);                                     \
    a1 = *(const float4*)(asrc + (t_)*32 + 4);                                 \
  }

#define WRITE_A(s_)                                                           \
  {                                                                           \
    s16x8 h_;                                                                 \
    h_[0] = (short)f2bf(a0.x); h_[1] = (short)f2bf(a0.y);                     \
    h_[2] = (short)f2bf(a0.z); h_[3] = (short)f2bf(a0.w);                     \
    h_[4] = (short)f2bf(a1.x); h_[5] = (short)f2bf(a1.y);                     \
    h_[6] = (short)f2bf(a1.z); h_[7] = (short)f2bf(a1.w);                     \
    *(s16x8*)&sA[s_][akw * 1024 + arow * 8] = h_;                             \
  }

#define STAGE_B(t_, s_)                                                       \
  {                                                                           \
    const unsigned short* cs_ = zp + (size_t)(c0 + (t_)) * 8192;              \
    _Pragma("unroll") for (int q = 0; q < 2; ++q) {                           \
      const int piece_ = w * 2 + q; /* 0..15, 1KB each */                     \
      gload_lds16((const char*)(cs_ + piece_ * 512) + l * 16,                 \
                  (char*)sB[s_] + piece_ * 1024);                             \
    }                                                                         \
  }

#define COMPUTE(s_)                                                           \
  {                                                                           \
    s16x8 af[4], bfr[4];                                                      \
    _Pragma("unroll") for (int mi = 0; mi < 4; ++mi) {                        \
      const int row_ = wm * 64 + mi * 16 + r16;                               \
      af[mi] = *(const s16x8*)&sA[s_][kw * 1024 + row_ * 8];                  \
    }                                                                         \
    _Pragma("unroll") for (int nj = 0; nj < 4; ++nj) {                        \
      const int col_ = wn * 64 + nj * 16 + r16;                               \
      bfr[nj] = *(const s16x8*)&sB[s_][kw * 2048 + col_ * 8];                 \
    }                                                                         \
    _Pragma("unroll") for (int mi = 0; mi < 4; ++mi)                          \
      _Pragma("unroll") for (int nj = 0; nj < 4; ++nj)                        \
        acc[mi][nj] = __builtin_amdgcn_mfma_f32_16x16x32_bf16(                \
            af[mi], bfr[nj], acc[mi][nj], 0, 0, 0);                           \
  }

  // prologue
  STAGE_B(0, 0);
  LOAD_A(0);
  WRITE_A(0);
  __syncthreads();

  for (int t = 0; t < steps; ++t) {
    const int cur = t & 1, nxt = cur ^ 1;
    if (t + 1 < steps) {
      LOAD_A(t + 1);
      STAGE_B(t + 1, nxt);
    }
    COMPUTE(cur);
    if (t + 1 < steps) WRITE_A(nxt);
    __syncthreads();
  }

#undef LOAD_A
#undef WRITE_A
#undef STAGE_B
#undef COMPUTE

  // epilogue: C/D layout col=lane&15, row=(lane>>4)*4+reg [verified m89/m91]
  unsigned short* cb = part + (size_t)ks * NN * DFF;
#pragma unroll
  for (int mi = 0; mi < 4; ++mi)
#pragma unroll
    for (int nj = 0; nj < 4; ++nj) {
      const int col = wn * 64 + nj * 16 + r16;
      const int row0 = m0 + wm * 64 + mi * 16 + kw * 4;
#pragma unroll
      for (int r = 0; r < 4; ++r)
        cb[(size_t)(row0 + r) * DFF + col] = f2bf(acc[mi][nj][r]);
    }
}

// ---- fused loss: neg norms, K-split partial sum (bf16), norms, LSE -----------
__global__ __launch_bounds__(256) void k_loss(const float* __restrict__ z,
                                              const unsigned short* __restrict__ part,
                                              const int* __restrict__ neg_idx,
                                              float* __restrict__ lpart, int KS) {
  __shared__ float sneg[NNEG * DFF];
  __shared__ float swsum[4];
  const int t = threadIdx.x;
  const int w = t >> 6, l = t & 63;
  for (int k = w; k < NNEG; k += 4) {
    const int idx = neg_idx[k];
    float4 v = *(const float4*)(z + (size_t)idx * DFF + l * 4);
    float ss = dot4(v, v);
#pragma unroll
    for (int off = 32; off > 0; off >>= 1) ss += __shfl_xor(ss, off);
    const float s = 1.0f / fmaxf(sqrtf(ss), 1e-12f);
    float4 o;
    o.x = v.x * s; o.y = v.y * s; o.z = v.z * s; o.w = v.w * s;
    *(float4*)&sneg[k * DFF + l * 4] = o;
  }
  __syncthreads();
  const int gw = blockIdx.x * 4 + w;  // 0..1023, 8 rows each
  float lsum = 0.f;
  for (int rr = 0; rr < 8; ++rr) {
    const int i = gw * 8 + rr;
    const float4 a = *(const float4*)(z + (size_t)i * DFF + l * 4);
    float4 p; p.x = 0.f; p.y = 0.f; p.z = 0.f; p.w = 0.f;
    for (int ksp = 0; ksp < KS; ++ksp) {
      const ushort4 q =
          *(const ushort4*)(part + ((size_t)ksp * NN + i) * DFF + l * 4);
      p.x += bf2f(q.x); p.y += bf2f(q.y); p.z += bf2f(q.z); p.w += bf2f(q.w);
    }
    float vals[13];
    vals[0] = dot4(a, a);
    vals[1] = dot4(p, p);
    vals[2] = dot4(a, p);
#pragma unroll
    for (int k = 0; k < NNEG; ++k) {
      const float4 nv = *(const float4*)&sneg[k * DFF + l * 4];
      vals[3 + k] = dot4(a, nv);
    }
#pragma unroll
    for (int off = 32; off > 0; off >>= 1)
#pragma unroll
      for (int j = 0; j < 13; ++j) vals[j] += __shfl_xor(vals[j], off);
    const float na = fmaxf(sqrtf(vals[0]), 1e-12f);
    const float npp = fmaxf(sqrtf(vals[1]), 1e-12f);
    const float ps = vals[2] / (na * npp) * 5.0f;  // 1/TEMP
    float S = 0.f;
#pragma unroll
    for (int k = 0; k < NNEG; ++k) S += expf(vals[3 + k] / na * 5.0f);
    lsum += logf(expf(ps) + S) - ps;
  }
  if (l == 0) swsum[w] = lsum;
  __syncthreads();
  if (t == 0) lpart[blockIdx.x] = swsum[0] + swsum[1] + swsum[2] + swsum[3];
}

__global__ void k_final(const float* __restrict__ lpart, float* __restrict__ out) {
  const int t = threadIdx.x;  // 64
  float v = lpart[t] + lpart[t + 64] + lpart[t + 128] + lpart[t + 192];
#pragma unroll
  for (int off = 32; off > 0; off >>= 1) v += __shfl_xor(v, off);
  if (t == 0) out[0] = v * (1.0f / (float)NN);
}

extern "C" void kernel_launch(void* const* d_in, const int* in_sizes, int n_in,
                              void* d_out, int out_size, void* d_ws, size_t ws_size,
                              hipStream_t stream) {
  const float* z = (const float*)d_in[0];
  const float* dm = (const float*)d_in[1];
  // d_in[2] edge_index, d_in[3] reliable_negatives: unused by the forward pass
  const int* neg_idx = (const int*)d_in[4];
  float* out = (float*)d_out;

  // workspace: zp (4MB) | partials bf16 (KS*4MB) | lpart (1KB)
  const size_t ZP = (size_t)NN * DFF * 2;  // 4 MB
  auto need = [ZP](size_t ks) { return ZP + ks * (size_t)NN * DFF * 2 + 1024; };
  int KS = 8;
  if (ws_size < need(8)) KS = (ws_size >= need(4)) ? 4 : 2;

  char* ws = (char*)d_ws;
  unsigned short* zp = (unsigned short*)ws;
  unsigned short* part = (unsigned short*)(ws + ZP);
  float* lpart = (float*)(ws + ZP + (size_t)KS * NN * DFF * 2);

  k_pack<<<dim3(128, 4), 256, 0, stream>>>(z, zp);
  k_gemm<<<64 * KS, 512, 0, stream>>>(dm, zp, part, KS);
  k_loss<<<256, 256, 0, stream>>>(z, part, neg_idx, lpart, KS);
  k_final<<<1, 64, 0, stream>>>(lpart, out);
}